// Round 2
// baseline (1992.525 us; speedup 1.0000x reference)
//
#include <hip/hip_runtime.h>

typedef __attribute__((ext_vector_type(8))) short short8;
typedef __attribute__((ext_vector_type(4))) float f32x4;
typedef __attribute__((ext_vector_type(4))) unsigned int u32x4;

#define DEV static __device__ __forceinline__

DEV unsigned short f2bf(float f){
  unsigned int u = __float_as_uint(f);
  u += 0x7FFFu + ((u >> 16) & 1u);
  return (unsigned short)(u >> 16);
}
DEV float bf2f(unsigned short h){ return __uint_as_float(((unsigned int)h) << 16); }

#define DTM 0.1f   /* DT*TAU_MEM_INV */
#define SYN 0.8f   /* 1 - DT*TAU_SYN_INV */
#define VTH 0.2f

// ---------------------------------------------------------------------------
// prep: build [tap][co][ci] bf16 hi/mid/lo weight digits, zero conv4 partial.
// hi+mid+lo represents w to ~2^-26 relative: effectively fp32-exact, and
// every MFMA product z*digit is exact since z in {0,1}.
// ---------------------------------------------------------------------------
__global__ __launch_bounds__(256) void prep_kernel(
    const float* __restrict__ w2, const float* __restrict__ w3, const float* __restrict__ w4,
    unsigned short* __restrict__ wb2h, unsigned short* __restrict__ wb2m, unsigned short* __restrict__ wb2l,
    unsigned short* __restrict__ wb3h, unsigned short* __restrict__ wb3m, unsigned short* __restrict__ wb3l,
    unsigned short* __restrict__ wb4h, unsigned short* __restrict__ wb4m, unsigned short* __restrict__ wb4l,
    float* __restrict__ partial)
{
  const int N2 = 9*128*64, N3 = 9*256*128, N4 = 9*256*256, NP = 2048*256;
  int tid = blockIdx.x*256 + threadIdx.x;
  if (tid < N2) {
    int tap = tid/(128*64), r = tid%(128*64), co = r>>6, ci = r&63;
    float w = w2[(co*64+ci)*9 + tap];
    unsigned short h = f2bf(w);       float r1 = w - bf2f(h);
    unsigned short m = f2bf(r1);      float r2 = r1 - bf2f(m);
    wb2h[tid] = h; wb2m[tid] = m; wb2l[tid] = f2bf(r2);
    return;
  }
  tid -= N2;
  if (tid < N3) {
    int tap = tid/(256*128), r = tid%(256*128), co = r>>7, ci = r&127;
    float w = w3[(co*128+ci)*9 + tap];
    unsigned short h = f2bf(w);       float r1 = w - bf2f(h);
    unsigned short m = f2bf(r1);      float r2 = r1 - bf2f(m);
    wb3h[tid] = h; wb3m[tid] = m; wb3l[tid] = f2bf(r2);
    return;
  }
  tid -= N3;
  if (tid < N4) {
    int tap = tid/(256*256), r = tid%(256*256), co = r>>8, ci = r&255;
    float w = w4[(co*256+ci)*9 + tap];
    unsigned short h = f2bf(w);       float r1 = w - bf2f(h);
    unsigned short m = f2bf(r1);      float r2 = r1 - bf2f(m);
    wb4h[tid] = h; wb4m[tid] = m; wb4l[tid] = f2bf(r2);
    return;
  }
  tid -= N4;
  if (tid < NP) partial[tid] = 0.f;
}

// ---------------------------------------------------------------------------
// K1: conv1 (fp32 direct, 3->64, 3x3 SAME) + LIF1. grid 512 = 32 imgs x 16 row-pairs
// ---------------------------------------------------------------------------
__global__ __launch_bounds__(256) void k1_conv1_lif(
    const float* __restrict__ x, const float* __restrict__ w1,
    float* __restrict__ v1, float* __restrict__ i1,
    unsigned short* __restrict__ z1, int t)
{
  __shared__ float xs[3][4][34];
  __shared__ float wl[27][64];
  int tid = threadIdx.x;
  int b = blockIdx.x >> 4, y0 = (blockIdx.x & 15) * 2;
  for (int e = tid; e < 3*4*34; e += 256) {
    int ci = e/136, r2 = e%136, r = r2/34, xi = r2%34;
    int y = y0 - 1 + r, xg = xi - 1;
    float v = 0.f;
    if (y >= 0 && y < 32 && xg >= 0 && xg < 32)
      v = x[((t*32 + b)*3 + ci)*1024 + y*32 + xg];
    xs[ci][r][xi] = v;
  }
  for (int e = tid; e < 27*64; e += 256) {
    int row = e >> 6, co = e & 63;
    int ci = row % 3, tap = row / 3, ky = tap/3, kx = tap%3;
    wl[row][co] = w1[((co*3+ci)*3+ky)*3+kx];
  }
  __syncthreads();
  int px = tid >> 2, cg = tid & 3;
  int ly = px >> 5, lx = px & 31;
  float acc[16];
#pragma unroll
  for (int q = 0; q < 16; q++) acc[q] = 0.f;
#pragma unroll
  for (int ky = 0; ky < 3; ky++)
#pragma unroll
    for (int kx = 0; kx < 3; kx++)
#pragma unroll
      for (int ci = 0; ci < 3; ci++) {
        float xv = xs[ci][ly+ky][lx+kx];
        const float4* wr = (const float4*)&wl[(ky*3+kx)*3+ci][cg*16];
#pragma unroll
        for (int q = 0; q < 4; q++) {
          float4 w4 = wr[q];
          acc[q*4+0] = fmaf(xv, w4.x, acc[q*4+0]);
          acc[q*4+1] = fmaf(xv, w4.y, acc[q*4+1]);
          acc[q*4+2] = fmaf(xv, w4.z, acc[q*4+2]);
          acc[q*4+3] = fmaf(xv, w4.w, acc[q*4+3]);
        }
      }
  int m_g = b*1024 + (y0+ly)*32 + lx;
  unsigned short zb[16];
#pragma unroll
  for (int q = 0; q < 4; q++) {
    int idx = m_g*64 + cg*16 + q*4;
    float vv[4] = {0.f,0.f,0.f,0.f}, ii[4] = {0.f,0.f,0.f,0.f};
    if (t != 0) {
      float4 v4 = *(const float4*)(v1+idx); float4 i4 = *(const float4*)(i1+idx);
      vv[0]=v4.x; vv[1]=v4.y; vv[2]=v4.z; vv[3]=v4.w;
      ii[0]=i4.x; ii[1]=i4.y; ii[2]=i4.z; ii[3]=i4.w;
    }
#pragma unroll
    for (int s = 0; s < 4; s++) {
      float vdec = vv[s] + DTM*((0.0f - vv[s]) + ii[s]);
      bool z = (vdec - VTH) > 0.0f;
      vv[s] = z ? 0.0f : vdec;
      ii[s] = SYN*ii[s] + acc[q*4+s];
      zb[q*4+s] = z ? 0x3F80 : 0;
    }
    *(float4*)(v1+idx) = make_float4(vv[0],vv[1],vv[2],vv[3]);
    *(float4*)(i1+idx) = make_float4(ii[0],ii[1],ii[2],ii[3]);
  }
  u32x4 za, zc;
  za[0]=zb[0]|((unsigned)zb[1]<<16); za[1]=zb[2]|((unsigned)zb[3]<<16);
  za[2]=zb[4]|((unsigned)zb[5]<<16); za[3]=zb[6]|((unsigned)zb[7]<<16);
  zc[0]=zb[8]|((unsigned)zb[9]<<16); zc[1]=zb[10]|((unsigned)zb[11]<<16);
  zc[2]=zb[12]|((unsigned)zb[13]<<16); zc[3]=zb[14]|((unsigned)zb[15]<<16);
  *(u32x4*)(z1 + m_g*64 + cg*16) = za;
  *(u32x4*)(z1 + m_g*64 + cg*16 + 8) = zc;
}

// ---------------------------------------------------------------------------
// Implicit-GEMM conv (3x3 SAME) over binary spikes, bf16 hi/mid/lo 3-digit
// MFMA, fused LIF epilogue (or K-split atomic partial for conv4).
// 256 thr = 4 waves, wave-tile = (MF*16) x 16; BN = 64 (NF=1).
// ---------------------------------------------------------------------------
template<int MF, int NF, int CIN_A, int WI, int HIM, int COUT, int CIN_W,
         bool POOL_IN, bool KSPLIT>
__global__ __launch_bounds__(256, 1) void conv_lif(
    const unsigned short* __restrict__ zsrc,
    const unsigned short* __restrict__ wbh, const unsigned short* __restrict__ wbm,
    const unsigned short* __restrict__ wbl,
    float* __restrict__ vst, float* __restrict__ ist,
    unsigned short* __restrict__ zout, float* __restrict__ partial, int t)
{
  constexpr int BM = MF*16;
  constexpr int BN = NF*16*4;
  constexpr int ROWS = BM / WI;
  constexpr int SLOTW = WI + 2;
  constexpr int SLOTS = (ROWS+2)*SLOTW;
  constexpr int CPH = CIN_A/64;
  constexpr int P = 9*CPH;
  constexpr int MT_PER_B = (HIM*WI)/BM;
  constexpr int NT = COUT/BN;
  constexpr int ACH = CIN_A/8;
  constexpr int ACHUNKS = SLOTS*ACH;
  constexpr int C_SRC = CIN_W;
  constexpr int BQ = BN/32;          // 16B chunks per thread to stage one B buf

  __shared__ __align__(16) char Al[SLOTS*CIN_A*2];
  __shared__ __align__(16) char Bh[BN*128];
  __shared__ __align__(16) char Bm[BN*128];
  __shared__ __align__(16) char Bl[BN*128];
  static_assert(SLOTS*CIN_A*2 + 3*BN*128 <= 64*1024, "LDS");

  int tid = threadIdx.x;
  int rem = blockIdx.x;
  int kh = 0;
  if constexpr (KSPLIT) { kh = rem & 1; rem >>= 1; }
  int nt = 0;
  if constexpr (NT > 1) { nt = rem % NT; rem /= NT; }
  int mt = rem;
  int b = mt / MT_PER_B;
  int y0 = (mt % MT_PER_B) * ROWS;
  int lane = tid & 63, wv = tid >> 6;
  int csrc0 = kh * 128;

  // ---- stage A (im2col source tile, pooled if requested) ----
  for (int ch = tid; ch < ACHUNKS; ch += 256) {
    int slot = ch / ACH, g = ch % ACH;
    int yr = slot / SLOTW, xr = slot % SLOTW;
    int y = y0 + yr - 1, xg = xr - 1;
    u32x4 val; val[0]=0; val[1]=0; val[2]=0; val[3]=0;
    if (y >= 0 && y < HIM && xg >= 0 && xg < WI) {
      if constexpr (POOL_IN) {
        const int W2 = WI*2;
        long base = ((long)(b*(HIM*2) + 2*y)*W2 + 2*xg)*C_SRC + csrc0 + g*8;
        u32x4 p0 = *(const u32x4*)(zsrc + base);
        u32x4 p1 = *(const u32x4*)(zsrc + base + C_SRC);
        u32x4 p2 = *(const u32x4*)(zsrc + base + (long)W2*C_SRC);
        u32x4 p3 = *(const u32x4*)(zsrc + base + (long)W2*C_SRC + C_SRC);
        val = (p0 | p1) | (p2 | p3);
      } else {
        long base = ((long)(b*HIM + y)*WI + xg)*C_SRC + g*8;
        val = *(const u32x4*)(zsrc + base);
      }
    }
    int addr = (slot*CIN_A + g*8)*2;
    addr ^= (slot & 7) << 4;
    *(u32x4*)(Al + addr) = val;
  }

  u32x4 bregh[BQ], bregm[BQ], bregl[BQ];
  auto loadB = [&](int p) {
    int tap = p / CPH, cs = p % CPH;
#pragma unroll
    for (int q = 0; q < BQ; q++) {
      int ch = q*256 + tid;
      int co = ch >> 3, g = ch & 7;
      long off = ((long)(tap*COUT + nt*BN + co))*CIN_W + kh*128 + cs*64 + g*8;
      bregh[q] = *(const u32x4*)(wbh + off);
      bregm[q] = *(const u32x4*)(wbm + off);
      bregl[q] = *(const u32x4*)(wbl + off);
    }
  };
  auto commitB = [&]() {
#pragma unroll
    for (int q = 0; q < BQ; q++) {
      int ch = q*256 + tid;
      int co = ch >> 3, g = ch & 7;
      int addr = (co*128 + g*16) ^ ((co & 7) << 4);
      *(u32x4*)(Bh + addr) = bregh[q];
      *(u32x4*)(Bm + addr) = bregm[q];
      *(u32x4*)(Bl + addr) = bregl[q];
    }
  };

  f32x4 acc[MF][NF];
#pragma unroll
  for (int mf = 0; mf < MF; mf++)
#pragma unroll
    for (int nf = 0; nf < NF; nf++) {
      acc[mf][nf][0]=0.f; acc[mf][nf][1]=0.f; acc[mf][nf][2]=0.f; acc[mf][nf][3]=0.f;
    }

  loadB(0); commitB();
  __syncthreads();

  for (int p = 0; p < P; p++) {
    if (p+1 < P) loadB(p+1);
    int tap = p / CPH, cs = p % CPH;
    int dy = tap/3 - 1, dx = tap%3 - 1;
#pragma unroll
    for (int ks = 0; ks < 2; ks++) {
      short8 a[MF], bh[NF], bm[NF], bl[NF];
#pragma unroll
      for (int mf = 0; mf < MF; mf++) {
        int pl = mf*16 + (lane & 15);
        int yl = pl / WI, xl = pl % WI;
        int slot = (yl + dy + 1)*SLOTW + (xl + dx + 1);
        int addr = (slot*CIN_A + cs*64 + ks*32 + (lane>>4)*8)*2;
        addr ^= (slot & 7) << 4;
        a[mf] = *(const short8*)(Al + addr);
      }
#pragma unroll
      for (int nf = 0; nf < NF; nf++) {
        int row = wv*(NF*16) + nf*16 + (lane & 15);
        int kb = ks*64 + (lane>>4)*16;
        int addr = (row*128 + kb) ^ ((row & 7) << 4);
        bh[nf] = *(const short8*)(Bh + addr);
        bm[nf] = *(const short8*)(Bm + addr);
        bl[nf] = *(const short8*)(Bl + addr);
      }
#pragma unroll
      for (int mf = 0; mf < MF; mf++)
#pragma unroll
        for (int nf = 0; nf < NF; nf++)
          acc[mf][nf] = __builtin_amdgcn_mfma_f32_16x16x32_bf16(a[mf], bh[nf], acc[mf][nf], 0, 0, 0);
#pragma unroll
      for (int mf = 0; mf < MF; mf++)
#pragma unroll
        for (int nf = 0; nf < NF; nf++)
          acc[mf][nf] = __builtin_amdgcn_mfma_f32_16x16x32_bf16(a[mf], bm[nf], acc[mf][nf], 0, 0, 0);
#pragma unroll
      for (int mf = 0; mf < MF; mf++)
#pragma unroll
        for (int nf = 0; nf < NF; nf++)
          acc[mf][nf] = __builtin_amdgcn_mfma_f32_16x16x32_bf16(a[mf], bl[nf], acc[mf][nf], 0, 0, 0);
    }
    __syncthreads();
    if (p+1 < P) { commitB(); __syncthreads(); }
  }

  // ---- epilogue ----
  int mbase = b*(HIM*WI) + y0*WI;
#pragma unroll
  for (int mf = 0; mf < MF; mf++)
#pragma unroll
    for (int nf = 0; nf < NF; nf++) {
      int chn = nt*BN + wv*(NF*16) + nf*16 + (lane & 15);
#pragma unroll
      for (int r = 0; r < 4; r++) {
        int pix = mf*16 + (lane>>4)*4 + r;
        long idx = (long)(mbase + pix)*COUT + chn;
        float cv = acc[mf][nf][r];
        if constexpr (KSPLIT) {
          atomicAdd(partial + idx, cv);
        } else {
          float vv = 0.f, ii = 0.f;
          if (t != 0) { vv = vst[idx]; ii = ist[idx]; }
          float vdec = vv + DTM*((0.0f - vv) + ii);
          bool z = (vdec - VTH) > 0.0f;
          vst[idx] = z ? 0.0f : vdec;
          ist[idx] = SYN*ii + cv;
          zout[idx] = z ? 0x3F80 : 0;
        }
      }
    }
}

// ---------------------------------------------------------------------------
// K5: LIF4 (from conv4 partial) + 2x2 pool + FC(4096->10) + LI + noise + max.
// ---------------------------------------------------------------------------
__global__ __launch_bounds__(256) void k5_lif4_fc(
    float* __restrict__ partial, float* __restrict__ v4, float* __restrict__ i4,
    const float* __restrict__ wfc, const float* __restrict__ noise,
    float* __restrict__ vl, float* __restrict__ il, float* __restrict__ dout, int t)
{
  __shared__ unsigned long long zbits[64][4];
  __shared__ unsigned long long pb[64];
  __shared__ float red[4][10];
  int tid = threadIdx.x, b = blockIdx.x;
  int px = tid >> 2, cq = tid & 3;
  long base = ((long)b*64 + px)*256 + cq*64;
  unsigned long long mask = 0ull;
#pragma unroll
  for (int q = 0; q < 16; q++) {
    float4 pv = *(const float4*)(partial + base + q*4);
    float vv[4] = {0.f,0.f,0.f,0.f}, ii[4] = {0.f,0.f,0.f,0.f};
    if (t != 0) {
      float4 v4v = *(const float4*)(v4 + base + q*4);
      float4 i4v = *(const float4*)(i4 + base + q*4);
      vv[0]=v4v.x; vv[1]=v4v.y; vv[2]=v4v.z; vv[3]=v4v.w;
      ii[0]=i4v.x; ii[1]=i4v.y; ii[2]=i4v.z; ii[3]=i4v.w;
    }
    float cv[4] = {pv.x, pv.y, pv.z, pv.w};
#pragma unroll
    for (int s = 0; s < 4; s++) {
      float vdec = vv[s] + DTM*((0.0f - vv[s]) + ii[s]);
      bool z = (vdec - VTH) > 0.0f;
      vv[s] = z ? 0.0f : vdec;
      ii[s] = SYN*ii[s] + cv[s];
      if (z) mask |= (1ull << (q*4 + s));
    }
    *(float4*)(v4 + base + q*4) = make_float4(vv[0],vv[1],vv[2],vv[3]);
    *(float4*)(i4 + base + q*4) = make_float4(ii[0],ii[1],ii[2],ii[3]);
    *(float4*)(partial + base + q*4) = make_float4(0.f,0.f,0.f,0.f);
  }
  zbits[px][cq] = mask;
  __syncthreads();
  if (tid < 64) {
    int py = tid >> 4, rm = tid & 15, pxx = rm >> 2, c4 = rm & 3;
    int p00 = (2*py)*8 + 2*pxx;
    pb[tid] = zbits[p00][c4] | zbits[p00+1][c4] | zbits[p00+8][c4] | zbits[p00+9][c4];
  }
  __syncthreads();
  float sums[10];
#pragma unroll
  for (int j = 0; j < 10; j++) sums[j] = 0.f;
  for (int q = 0; q < 16; q++) {
    int k = q*256 + tid;
    int c = k >> 4, s = k & 15, yy = s >> 2, xx = s & 3;
    unsigned long long bits = pb[yy*16 + xx*4 + (c >> 6)];
    if ((bits >> (c & 63)) & 1ull) {
#pragma unroll
      for (int j = 0; j < 10; j++) sums[j] += wfc[j*4096 + k];
    }
  }
#pragma unroll
  for (int j = 0; j < 10; j++) {
    float v = sums[j];
    for (int off = 32; off; off >>= 1) v += __shfl_xor(v, off);
    if ((tid & 63) == 0) red[tid>>6][j] = v;
  }
  __syncthreads();
  if (tid < 10) {
    float o = red[0][tid] + red[1][tid] + red[2][tid] + red[3][tid];
    float vo = 0.f, io = 0.f;
    if (t != 0) { vo = vl[b*10 + tid]; io = il[b*10 + tid]; }
    float vn = vo + DTM*((0.0f - vo) + io);
    float inw = SYN*io + o;
    vl[b*10 + tid] = vn; il[b*10 + tid] = inw;
    float volt = vn + 0.001f*noise[((long)t*32 + b)*10 + tid];
    dout[b*10 + tid] = (t == 0) ? volt : fmaxf(dout[b*10 + tid], volt);
  }
}

// ---------------------------------------------------------------------------
extern "C" void kernel_launch(void* const* d_in, const int* in_sizes, int n_in,
                              void* d_out, int out_size, void* d_ws, size_t ws_size,
                              hipStream_t stream)
{
  const float* x     = (const float*)d_in[0];
  const float* noise = (const float*)d_in[1];
  const float* w1    = (const float*)d_in[2];
  const float* w2    = (const float*)d_in[3];
  const float* w3    = (const float*)d_in[4];
  const float* w4    = (const float*)d_in[5];
  const float* wfc   = (const float*)d_in[6];
  float* dout = (float*)d_out;

  char* ws = (char*)d_ws;
  size_t off = 0;
  auto alloc = [&](size_t bytes) -> char* {
    char* p = ws + off;
    off = (off + bytes + 255) & ~(size_t)255;
    return p;
  };
  float* v1 = (float*)alloc(2097152u*4); float* i1 = (float*)alloc(2097152u*4);
  float* v2 = (float*)alloc(4194304u*4); float* i2 = (float*)alloc(4194304u*4);
  float* v3 = (float*)alloc(2097152u*4); float* i3 = (float*)alloc(2097152u*4);
  float* v4 = (float*)alloc(524288u*4);  float* i4 = (float*)alloc(524288u*4);
  unsigned short* z1 = (unsigned short*)alloc(2097152u*2);
  unsigned short* z2 = (unsigned short*)alloc(4194304u*2);
  unsigned short* z3 = (unsigned short*)alloc(2097152u*2);
  float* partial = (float*)alloc(524288u*4);
  float* vl = (float*)alloc(1280);
  float* il = (float*)alloc(1280);
  unsigned short* wb2h = (unsigned short*)alloc(73728u*2);
  unsigned short* wb2m = (unsigned short*)alloc(73728u*2);
  unsigned short* wb2l = (unsigned short*)alloc(73728u*2);
  unsigned short* wb3h = (unsigned short*)alloc(294912u*2);
  unsigned short* wb3m = (unsigned short*)alloc(294912u*2);
  unsigned short* wb3l = (unsigned short*)alloc(294912u*2);
  unsigned short* wb4h = (unsigned short*)alloc(589824u*2);
  unsigned short* wb4m = (unsigned short*)alloc(589824u*2);
  unsigned short* wb4l = (unsigned short*)alloc(589824u*2);

  prep_kernel<<<5792, 256, 0, stream>>>(w2, w3, w4,
      wb2h, wb2m, wb2l, wb3h, wb3m, wb3l, wb4h, wb4m, wb4l, partial);

  for (int t = 0; t < 16; t++) {
    k1_conv1_lif<<<512, 256, 0, stream>>>(x, w1, v1, i1, z1, t);
    // conv2: 64->128 @32x32, BM=128 BN=64, grid 32*8*2
    conv_lif<8,1,64,32,32,128,64,false,false><<<512, 256, 0, stream>>>(
        z1, wb2h, wb2m, wb2l, v2, i2, z2, nullptr, t);
    // conv3: 128->256 @16x16 (pooled in), BM=64 BN=64, grid 32*4*4
    conv_lif<4,1,128,16,16,256,128,true,false><<<512, 256, 0, stream>>>(
        z2, wb3h, wb3m, wb3l, v3, i3, z3, nullptr, t);
    // conv4: 256->256 @8x8 (pooled in), BM=32 BN=64, K-split 2, grid 32*2*4*2
    conv_lif<2,1,128,8,8,256,256,true,true><<<512, 256, 0, stream>>>(
        z3, wb4h, wb4m, wb4l, nullptr, nullptr, nullptr, partial, t);
    k5_lif4_fc<<<32, 256, 0, stream>>>(partial, v4, i4, wfc, noise, vl, il, dout, t);
  }
}